// Round 12
// baseline (65.275 us; speedup 1.0000x reference)
//
#include <hip/hip_runtime.h>
#include <math.h>

// HistDRDoubleConv on gfx950 — 3 kernels; convs rewritten on MFMA.
// B=8, Cin=Cmid=Cout=8, H=W=256, R=8. Pool windows at rows/cols {0,85,170}, k=86.
//  K1 prep:  rowsum(x)->rs1 ; xh4 = fp16 8-ch-interleaved px records ; regmap
//  K2 conv1: inline buildK1(rs1)->B-frags ; MFMA all 64 (reg,oc) per px ;
//            gather selected region + BN/ReLU -> y1h4 ; epilogue rs2
//  K3 conv2: same with (rs2, layer-2 weights) -> out (f32)
// MFMA mfma_f32_16x16x32_f16: M=16 px, N=64 (reg*8+oc), K=72 pad 96.
// A: lane l holds X[px = l&15][k = (l>>4)*8+j] -> one ds_read_b128 of the
//    8-channel record at (row+dy-1, x+dx-1), tap = k>>3 (m92-verified layout).
// B: lane l holds K[k=(l>>4)*8+j][n = l&15 of N-tile] -> preloaded in VGPRs.
// C/D: col = lane&15 (n), row = (lane>>4)*4+j (px)  [learn_hip m89-verified].

#define HWPX 65536
#define HDIM 256

typedef __fp16 h2v __attribute__((ext_vector_type(2)));
typedef __fp16 v8h __attribute__((ext_vector_type(8)));
typedef float v4f __attribute__((ext_vector_type(4)));

union UH { uint u; h2v h; };
union U4V8 { uint4 u4; v8h h8; };

// ---------------- prep: rowsums + 8ch-interleaved fp16 records + regmap -----
__global__ __launch_bounds__(256) void prep_kernel(const float* __restrict__ x,
                                                   const float* __restrict__ hist,
                                                   float* __restrict__ rs1,
                                                   uint4* __restrict__ xh4,
                                                   unsigned char* __restrict__ regmap) {
  int u = blockIdx.x, t = threadIdx.x, w = t >> 6, l = t & 63;
  if (u < 512) {
    int b = u & 7, rg = u >> 3;          // batch-per-XCD
    int row = rg * 4 + w;
    const float* base = x + (size_t)b * 8 * HWPX + row * HDIM + l * 4;
    float4 ch[8];
#pragma unroll
    for (int c = 0; c < 8; c++) ch[c] = *(const float4*)(base + (size_t)c * HWPX);
    uint4* dst = xh4 + ((size_t)b * 256 + row) * 256 + l * 4;
#pragma unroll
    for (int p = 0; p < 4; p++) {
      UH h0, h1, h2, h3;
      h0.h = __builtin_amdgcn_cvt_pkrtz((&ch[0].x)[p], (&ch[1].x)[p]);
      h1.h = __builtin_amdgcn_cvt_pkrtz((&ch[2].x)[p], (&ch[3].x)[p]);
      h2.h = __builtin_amdgcn_cvt_pkrtz((&ch[4].x)[p], (&ch[5].x)[p]);
      h3.h = __builtin_amdgcn_cvt_pkrtz((&ch[6].x)[p], (&ch[7].x)[p]);
      dst[p] = make_uint4(h0.u, h1.u, h2.u, h3.u);
    }
    // rowsums: 8 channels x 3 column windows
#pragma unroll
    for (int c = 0; c < 8; c++) {
      float s0 = 0.f, s1 = 0.f, s2 = 0.f;
#pragma unroll
      for (int p = 0; p < 4; p++) {
        int px = l * 4 + p;
        float val = (&ch[c].x)[p];
        if (px <= 85) s0 += val;
        if (px >= 85 && px <= 170) s1 += val;
        if (px >= 170) s2 += val;
      }
#pragma unroll
      for (int off = 32; off >= 1; off >>= 1) {
        s0 += __shfl_xor(s0, off);
        s1 += __shfl_xor(s1, off);
        s2 += __shfl_xor(s2, off);
      }
      if (l == 0) {
        float* q = rs1 + ((size_t)(b * 8 + c) * 256 + row) * 3;
        q[0] = s0; q[1] = s1; q[2] = s2;
      }
    }
  } else {
    int u2 = u - 512;
    int b = u2 & 7, rg = u2 >> 3;
    int row = rg * 4 + w;
    int x0 = l * 4;
    const float* hp = hist + (size_t)b * 8 * HWPX + row * HDIM + x0;
    float4 hv[8];
#pragma unroll
    for (int r = 0; r < 8; r++) hv[r] = *(const float4*)(hp + (size_t)r * HWPX);
    uchar4 rg4;
#pragma unroll
    for (int p = 0; p < 4; p++) {
      float best = (&hv[0].x)[p];
      int reg = 0;
#pragma unroll
      for (int r = 1; r < 8; r++) {
        float q = (&hv[r].x)[p];
        if (q > best) { best = q; reg = r; }   // strict > == JAX first-max
      }
      (&rg4.x)[p] = (unsigned char)reg;
    }
    *(uchar4*)(regmap + (size_t)b * HWPX + row * HDIM + x0) = rg4;
  }
}

// ---------------- conv: buildK -> B-frags ; MFMA ; gather+BN/ReLU -----------
template <int LAYER>
__global__ __launch_bounds__(256, 2) void conv_kernel(
    const uint4* __restrict__ in4, const unsigned char* __restrict__ regmap,
    const float* __restrict__ rs,
    const float* __restrict__ wa, const float* __restrict__ ba,
    const float* __restrict__ wb, const float* __restrict__ bb,
    const float* __restrict__ g, const float* __restrict__ be,
    const float* __restrict__ m, const float* __restrict__ v,
    uint* __restrict__ outh, float* __restrict__ outf,
    float* __restrict__ rs2out) {
  __shared__ uint4 xs[6][260];                   // 24960 B staged input tile
  __shared__ __align__(16) float Dbuf[4][64][20]; // 20480 B per-wave D scratch
  __shared__ uint4 Bf[4][3][64];                 // 12288 B B-fragments
  __shared__ float pp[72][3];
  __shared__ float pP[8][9];
  __shared__ float hh[576];
  __shared__ float bns[8], bnsh[8];
  __shared__ unsigned char rm[4][256];

  int bid = blockIdx.x;
  int b = bid & 7, rg = bid >> 3, r0 = rg * 4;   // batch-per-XCD
  int t = threadIdx.x, w = t >> 6, l = t & 63;

  // ---- stage input tile (rows r0-1..r0+4, halo cols zeroed) ----
  for (int i = t; i < 6 * 256; i += 256) {
    int dy = i >> 8, px = i & 255;
    int yy = r0 - 1 + dy;
    uint4 val = make_uint4(0, 0, 0, 0);
    if ((unsigned)yy < 256u) val = in4[((size_t)b * 256 + yy) * 256 + px];
    xs[dy][px + 1] = val;
  }
  if (t < 12) {
    int rr = t % 6, cc = (t < 6) ? 0 : 257;
    xs[rr][cc] = make_uint4(0, 0, 0, 0);
  }
  // ---- stage regmap rows ----
  ((uint*)rm)[t] = *(const uint*)(regmap + (size_t)b * HWPX + (r0 + (t >> 6)) * HDIM + (t & 63) * 4);

  // ---- inline buildK: pool from rowsums ----
  if (t < 216) {
    int u = t / 3, part = t - 3 * (t / 3);
    int c = u / 9, ij = u % 9, i = ij / 3, j = ij % 3;
    int rr0 = 85 * i + part * 29;
    int cnt = (part == 2) ? 28 : 29;
    const float* q = rs + ((size_t)(b * 8 + c) * 256 + rr0) * 3 + j;
    float s = 0.f;
    for (int k = 0; k < cnt; k++) s += q[k * 3];
    pp[u][part] = s;
  }
  if (t >= 248) {
    int oc = t - 248;
    float s = g[oc] * rsqrtf(v[oc] + 1e-5f);
    bns[oc] = s;
    bnsh[oc] = be[oc] - m[oc] * s;
  }
  __syncthreads();
  if (t < 72) pP[t / 9][t % 9] = (pp[t][0] + pp[t][1] + pp[t][2]) * (1.f / 7396.f);
  __syncthreads();
  for (int u = t; u < 576; u += 256) {
    int o = u / 9, ij = u - o * 9;
    float z = ba[o];
#pragma unroll
    for (int c = 0; c < 8; c++) z += pP[c][ij] * wa[o * 8 + c];
    hh[u] = 1.f / (1.f + expf(-z));
  }
  __syncthreads();
  // ---- build B-fragments: thread t -> (nt = t>>6, lane l2 = t&63) ----
  {
    int nt = t >> 6, l2 = t & 63;
    int n = nt * 16 + (l2 & 15);
    int reg = n >> 3, oc = n & 7;
#pragma unroll
    for (int ks = 0; ks < 3; ks++) {
      int tap = ks * 4 + (l2 >> 4);
      uint4 rec = make_uint4(0, 0, 0, 0);
      if (tap < 9) {
        float hv[8];
#pragma unroll
        for (int cc = 0; cc < 8; cc++) hv[cc] = hh[(reg * 8 + cc) * 9 + tap];
        float vj[8];
#pragma unroll
        for (int j = 0; j < 8; j++) {
          int rowk = reg * 64 + oc * 8 + j;          // ci = j
          float val = bb[rowk];
#pragma unroll
          for (int cc = 0; cc < 8; cc++) val += hv[cc] * wb[rowk * 8 + cc];
          vj[j] = val;
        }
        UH p0, p1, p2, p3;
        p0.h = __builtin_amdgcn_cvt_pkrtz(vj[0], vj[1]);
        p1.h = __builtin_amdgcn_cvt_pkrtz(vj[2], vj[3]);
        p2.h = __builtin_amdgcn_cvt_pkrtz(vj[4], vj[5]);
        p3.h = __builtin_amdgcn_cvt_pkrtz(vj[6], vj[7]);
        rec = make_uint4(p0.u, p1.u, p2.u, p3.u);
      }
      Bf[nt][ks][l2] = rec;
    }
  }
  __syncthreads();

  // ---- preload B fragments into VGPRs (48 regs) ----
  U4V8 Bfr[4][3];
#pragma unroll
  for (int nt = 0; nt < 4; nt++)
#pragma unroll
    for (int ks = 0; ks < 3; ks++)
      Bfr[nt][ks].u4 = Bf[nt][ks][l];

  int row = r0 + w;
  int ocp = l >> 4;                     // this lane's output-channel pair
  float bn_s0 = bns[2 * ocp], bn_h0 = bnsh[2 * ocp];
  float bn_s1 = bns[2 * ocp + 1], bn_h1 = bnsh[2 * ocp + 1];
  float rsm[2][3] = {{0.f, 0.f, 0.f}, {0.f, 0.f, 0.f}};

  for (int mt = 0; mt < 16; mt++) {
    // A fragments: one b128 per K-step
    U4V8 A[3];
#pragma unroll
    for (int ks = 0; ks < 3; ks++) {
      int tap = ks * 4 + (l >> 4);
      if (tap > 8) tap = 8;             // k>=72: B is zero, any valid A
      int dy = tap / 3, dx = tap - dy * 3;
      A[ks].u4 = xs[w + dy][mt * 16 + (l & 15) + dx];
    }
    v4f acc[4];
#pragma unroll
    for (int nt = 0; nt < 4; nt++) {
      v4f z = {0.f, 0.f, 0.f, 0.f};
      z = __builtin_amdgcn_mfma_f32_16x16x32_f16(A[0].h8, Bfr[nt][0].h8, z, 0, 0, 0);
      z = __builtin_amdgcn_mfma_f32_16x16x32_f16(A[1].h8, Bfr[nt][1].h8, z, 0, 0, 0);
      z = __builtin_amdgcn_mfma_f32_16x16x32_f16(A[2].h8, Bfr[nt][2].h8, z, 0, 0, 0);
      acc[nt] = z;
    }
    // D -> LDS scratch: lane holds 4 px rows at col nt*16+(l&15)
#pragma unroll
    for (int nt = 0; nt < 4; nt++) {
      int col = nt * 16 + (l & 15);
      int px0 = (l >> 4) * 4;
      *(v4f*)&Dbuf[w][col][px0] = acc[nt];
    }
    // gather selected region (within-wave; hw waits handle the RAW)
    int gx = l & 15;
    int px = mt * 16 + gx;
    int reg = rm[w][px];
    int c0 = reg * 8 + ocp * 2;
    float o0 = Dbuf[w][c0][gx];
    float o1 = Dbuf[w][c0 + 1][gx];
    o0 = fmaxf(o0 * bn_s0 + bn_h0, 0.f);
    o1 = fmaxf(o1 * bn_s1 + bn_h1, 0.f);
    if (LAYER == 1) {
      UH pk;
      pk.h = __builtin_amdgcn_cvt_pkrtz(o0, o1);
      outh[(((size_t)b * 256 + row) * 256 + px) * 4 + ocp] = pk.u;
      if (px <= 85)               { rsm[0][0] += o0; rsm[1][0] += o1; }
      if (px >= 85 && px <= 170)  { rsm[0][1] += o0; rsm[1][1] += o1; }
      if (px >= 170)              { rsm[0][2] += o0; rsm[1][2] += o1; }
    } else {
      outf[((size_t)(b * 8 + 2 * ocp)) * HWPX + row * HDIM + px] = o0;
      outf[((size_t)(b * 8 + 2 * ocp + 1)) * HWPX + row * HDIM + px] = o1;
    }
  }

  if (LAYER == 1) {
    // reduce row partials across the 16 px-lanes of each ocp group
#pragma unroll
    for (int i = 0; i < 2; i++)
#pragma unroll
      for (int j = 0; j < 3; j++) {
#pragma unroll
        for (int off = 1; off <= 8; off <<= 1)
          rsm[i][j] += __shfl_xor(rsm[i][j], off);
      }
    if ((l & 15) == 0) {
#pragma unroll
      for (int i = 0; i < 2; i++) {
        float* q = rs2out + ((size_t)(b * 8 + 2 * ocp + i) * 256 + row) * 3;
        q[0] = rsm[i][0]; q[1] = rsm[i][1]; q[2] = rsm[i][2];
      }
    }
  }
}

extern "C" void kernel_launch(void* const* d_in, const int* in_sizes, int n_in,
                              void* d_out, int out_size, void* d_ws, size_t ws_size,
                              hipStream_t stream) {
  const float* x    = (const float*)d_in[0];
  const float* hist = (const float*)d_in[1];
  const float* w1a  = (const float*)d_in[2];
  const float* b1a  = (const float*)d_in[3];
  const float* w1b  = (const float*)d_in[4];
  const float* b1b  = (const float*)d_in[5];
  const float* g1   = (const float*)d_in[6];
  const float* be1  = (const float*)d_in[7];
  const float* m1   = (const float*)d_in[8];
  const float* v1   = (const float*)d_in[9];
  const float* w2a  = (const float*)d_in[10];
  const float* b2a  = (const float*)d_in[11];
  const float* w2b  = (const float*)d_in[12];
  const float* b2b  = (const float*)d_in[13];
  const float* g2   = (const float*)d_in[14];
  const float* be2  = (const float*)d_in[15];
  const float* m2   = (const float*)d_in[16];
  const float* v2   = (const float*)d_in[17];
  float* outp = (float*)d_out;

  char* ws = (char*)d_ws;
  unsigned char* regmap = (unsigned char*)ws;            // 524288
  uint4* xh4  = (uint4*)(ws + 524288);                   // 8388608
  uint4* y1h4 = (uint4*)(ws + 8912896);                  // 8388608
  float* rs1 = (float*)(ws + 17301504);                  // 98304
  float* rs2 = (float*)(ws + 17399808);                  // 98304

  prep_kernel<<<1024, 256, 0, stream>>>(x, hist, rs1, xh4, regmap);
  conv_kernel<1><<<512, 256, 0, stream>>>(xh4, regmap, rs1, w1a, b1a, w1b, b1b,
                                          g1, be1, m1, v1, (uint*)y1h4, nullptr, rs2);
  conv_kernel<2><<<512, 256, 0, stream>>>(y1h4, regmap, rs2, w2a, b2a, w2b, b2b,
                                          g2, be2, m2, v2, nullptr, outp, nullptr);
}